// Round 7
// baseline (300.102 us; speedup 1.0000x reference)
//
#include <hip/hip_runtime.h>
#include <math.h>

// minGRU: hg = x@Whg^T (bf16 MFMA, 256^2, m201-window schedule) -> gates+scan (fp32)
//         -> out = h@Wout^T (bf16 MFMA), LDS-transposed coalesced epilogues
// x[4,4096,1024] f32, W_hg[2048,1024], W_out[1024,1024], out[4,4096,1024] f32

typedef unsigned short ushort_t;
typedef __attribute__((ext_vector_type(4))) float f32x4;
typedef __attribute__((ext_vector_type(8))) __bf16 bf16x8;
typedef __attribute__((ext_vector_type(8))) unsigned short u16x8;
typedef __attribute__((ext_vector_type(4))) unsigned short u16x4;

constexpr int Bsz  = 4;
constexpr int S    = 4096;
constexpr int Din  = 1024;
constexpr int Dh   = 1024;
constexpr int M    = Bsz * S;      // 16384
constexpr int NCH  = 64;           // scan chunks along S
constexpr int CL   = S / NCH;      // 64

__device__ __forceinline__ unsigned short f2bf(float f) {
    unsigned int u = __float_as_uint(f);
    unsigned int r = (u + 0x7fffu + ((u >> 16) & 1u)) >> 16;   // RTN-even
    return (unsigned short)r;
}
__device__ __forceinline__ float bf2f(unsigned short u) {
    return __uint_as_float(((unsigned int)u) << 16);
}
__device__ __forceinline__ float sigf(float x) {
    x = fminf(fmaxf(x, -30.f), 30.f);
    return 1.0f / (1.0f + __expf(-x));
}
__device__ __forceinline__ void gld_lds16(const ushort_t* g, ushort_t* l) {
    __builtin_amdgcn_global_load_lds(
        (const __attribute__((address_space(1))) void*)g,
        (__attribute__((address_space(3))) void*)l, 16, 0, 0);
}

// one kernel converting all three f32 inputs to bf16
__global__ __launch_bounds__(256) void cvt_all(
    const float* __restrict__ x, const float* __restrict__ whg,
    const float* __restrict__ wout,
    ushort_t* __restrict__ xb, ushort_t* __restrict__ whgb,
    ushort_t* __restrict__ woutb)
{
    constexpr int NX = M * Din / 8;          // 2097152
    constexpr int NW = 2048 * 1024 / 8;      // 262144
    const int i = blockIdx.x * 256 + threadIdx.x;
    const float* src; ushort_t* dst; int k;
    if (i < NX)            { src = x;    dst = xb;    k = i; }
    else if (i < NX + NW)  { src = whg;  dst = whgb;  k = i - NX; }
    else                   { src = wout; dst = woutb; k = i - NX - NW; }
    const float4 a = ((const float4*)src)[(size_t)k * 2];
    const float4 b = ((const float4*)src)[(size_t)k * 2 + 1];
    u16x8 o;
    o[0] = f2bf(a.x); o[1] = f2bf(a.y); o[2] = f2bf(a.z); o[3] = f2bf(a.w);
    o[4] = f2bf(b.x); o[5] = f2bf(b.y); o[6] = f2bf(b.z); o[7] = f2bf(b.w);
    ((u16x8*)dst)[k] = o;
}

// C[M x N] = A[M x K] * B[N x K]^T, bf16 in, f32 accum.
// 256x256 tile, 8 waves (2Mx4N), phases of K=32, 4-slot LDS ring (round-3
// layout: slot [256 rows][32 cols] bf16, subtiled [16][32], st_16x32 swizzle,
// pre-swizzled global source, measured 0 bank conflicts).
// m201 window order per phase p:
//   reads(p) 12x ds_read_b128; stage(p+2) 4x gload_lds; barrier;
//   lgkmcnt(0); setprio(1); 32 MFMA; setprio(0); vmcnt; barrier2.
// FIFO (per wave): entering p outstanding = stage(p+1) = 4; +stage(p+2) = 8;
//   post-MFMA vmcnt(4) drains stage(p+1) -> barrier2 -> reads(p+1) safe.
//   Tail: p=P-2 -> vmcnt(0) (stage(P) not issued); p=P-1 -> none.
// WAR: stage(p+2) targets slot (p-2)&3, last read at phase p-2, 2 barrier
//   pairs earlier -> safe.
template<bool OUT_BF16>
__global__ __launch_bounds__(512, 2) void gemm256(
    const ushort_t* __restrict__ A, int lda,
    const ushort_t* __restrict__ B, int ldb,
    void* __restrict__ Cout, int ldc, int K, int nbx_log2)
{
    __shared__ ushort_t lds[4][2][8192];   // [slot][A=0/B=1][256*32] = 128 KiB
    char* const ldsb = (char*)&lds[0][0][0];

    const int P = K >> 5;                  // phases (K=1024 -> 32)

    // XCD-bijective block swizzle (gridDim.x % 8 == 0)
    const int nwg = gridDim.x;
    const int cpx = nwg >> 3;
    const int bid = blockIdx.x;
    const int swz = (bid & 7) * cpx + (bid >> 3);
    const int bx  = swz & ((1 << nbx_log2) - 1);
    const int by  = swz >> nbx_log2;
    const int bm0 = by * 256;
    const int bn0 = bx * 256;

    const int t  = threadIdx.x;
    const int w  = t >> 6;           // wave 0..7
    const int l  = t & 63;
    const int wr = w >> 2;           // 0..1 -> 128 rows
    const int wc = w & 3;            // 0..3 -> 64 cols

    // fragment read offsets (elements), swizzle folded in
    const int fr = l & 15;
    const int kg = l >> 4;
    const int qp = kg ^ (((fr >> 3) & 1) << 1);
    const int a_base = wr * 4096 + fr * 32 + qp * 8;   // + i*512
    const int b_base = wc * 2048 + fr * 32 + qp * 8;   // + j*512

    // staging: lane -> (subtile row, quarter); pre-swizzled global source
    const int rs = l >> 2;
    const int lq = (l & 3) ^ (((rs >> 3) & 1) << 1);
    const ushort_t* gA0 = A + (size_t)(bm0 + w * 16 + rs) * lda + lq * 8;
    const ushort_t* gA1 = gA0 + (size_t)128 * lda;
    const ushort_t* gB0 = B + (size_t)(bn0 + w * 16 + rs) * ldb + lq * 8;
    const ushort_t* gB1 = gB0 + (size_t)128 * ldb;

    f32x4 acc[8][4];
    #pragma unroll
    for (int i = 0; i < 8; ++i)
        #pragma unroll
        for (int j = 0; j < 4; ++j)
            acc[i][j] = (f32x4){0.f, 0.f, 0.f, 0.f};

    auto stage = [&](int p) {   // 4 global_load_lds for phase p's slot
        const int s2 = p & 3;
        const int ko = p * 32;
        gld_lds16(gA0 + ko, &lds[s2][0][w * 512]);
        gld_lds16(gA1 + ko, &lds[s2][0][w * 512 + 4096]);
        gld_lds16(gB0 + ko, &lds[s2][1][w * 512]);
        gld_lds16(gB1 + ko, &lds[s2][1][w * 512 + 4096]);
    };

    // prologue: stage phases 0 and 1 (8 loads in flight)
    stage(0);
    stage(1);
    asm volatile("s_waitcnt vmcnt(4)" ::: "memory");   // slot 0 landed
    __builtin_amdgcn_s_barrier();
    __builtin_amdgcn_sched_barrier(0);

    #pragma unroll 1
    for (int p = 0; p < P; ++p) {
        const int s = p & 3;
        const ushort_t* la = &lds[s][0][0];
        const ushort_t* lb = &lds[s][1][0];
        bf16x8 af[8], bfr[4];
        #pragma unroll
        for (int i = 0; i < 8; ++i)
            af[i] = *reinterpret_cast<const bf16x8*>(&la[a_base + i * 512]);
        #pragma unroll
        for (int j = 0; j < 4; ++j)
            bfr[j] = *reinterpret_cast<const bf16x8*>(&lb[b_base + j * 512]);
        if (p + 2 < P) stage(p + 2);
        __builtin_amdgcn_sched_barrier(0);
        __builtin_amdgcn_s_barrier();
        asm volatile("s_waitcnt lgkmcnt(0)" ::: "memory");
        __builtin_amdgcn_sched_barrier(0);
        __builtin_amdgcn_s_setprio(1);
        #pragma unroll
        for (int i = 0; i < 8; ++i)
            #pragma unroll
            for (int j = 0; j < 4; ++j)
                acc[i][j] = __builtin_amdgcn_mfma_f32_16x16x32_bf16(
                    af[i], bfr[j], acc[i][j], 0, 0, 0);
        __builtin_amdgcn_s_setprio(0);
        __builtin_amdgcn_sched_barrier(0);
        if (p <= P - 3)
            asm volatile("s_waitcnt vmcnt(4)" ::: "memory");
        else if (p == P - 2)
            asm volatile("s_waitcnt vmcnt(0)" ::: "memory");
        __builtin_amdgcn_s_barrier();   // barrier2: next phase's reads safe
    }

    // ---- epilogue: per-wave LDS transpose -> coalesced stores ----
    // After final barrier2 all waves' ds reads are complete; LDS reusable.
    // acc[i][j][r] holds C(row = bm0+wr*128+i*16+kg*4+r, col = bn0+wc*64+j*16+fr).
    // Per-wave region: 16 rows x 68 f32 (stride 272 B): write 2-way banks,
    // read ~4-way; stores: f32 path 16 lanes x 16B = 256B segments,
    // bf16 path 16 lanes x 8B = 128B segments.
    float* lw = (float*)(ldsb + w * 4352);
    #pragma unroll 1
    for (int i = 0; i < 8; ++i) {
        asm volatile("s_waitcnt lgkmcnt(0)" ::: "memory");  // prev iter reads done
        __builtin_amdgcn_sched_barrier(0);
        #pragma unroll
        for (int j = 0; j < 4; ++j)
            #pragma unroll
            for (int r = 0; r < 4; ++r)
                lw[(kg * 4 + r) * 68 + j * 16 + fr] = acc[i][j][r];
        asm volatile("s_waitcnt lgkmcnt(0)" ::: "memory");
        __builtin_amdgcn_sched_barrier(0);
        #pragma unroll
        for (int ci = 0; ci < 4; ++ci) {
            const int rr  = ci * 4 + kg;
            const f32x4 v = *(const f32x4*)&lw[rr * 68 + fr * 4];
            const int row = bm0 + wr * 128 + i * 16 + rr;
            const int col = bn0 + wc * 64 + fr * 4;
            if (OUT_BF16) {
                u16x4 o4;
                o4[0] = f2bf(v[0]); o4[1] = f2bf(v[1]);
                o4[2] = f2bf(v[2]); o4[3] = f2bf(v[3]);
                *(u16x4*)((ushort_t*)Cout + (size_t)row * ldc + col) = o4;
            } else {
                *(f32x4*)((float*)Cout + (size_t)row * ldc + col) = v;
            }
        }
        __builtin_amdgcn_sched_barrier(0);
    }
}

// ---- scan over S in 3 stages; gates recomputed from bf16 hg on the fly ----

__global__ __launch_bounds__(256) void scan_stage1(
    const ushort_t* __restrict__ hg, float* __restrict__ Abuf,
    float* __restrict__ hlbuf)
{
    const int g     = blockIdx.x * 256 + threadIdx.x;
    const int d     = g & (Dh - 1);
    const int chunk = (g >> 10) & (NCH - 1);
    const int b     = g >> 16;
    const size_t rowbase = (size_t)(b * S + chunk * CL) * 2048;
    float h = 0.0f, Aacc = 1.0f;
    #pragma unroll 4
    for (int i = 0; i < CL; ++i) {
        const float hid  = bf2f(hg[rowbase + (size_t)i * 2048 + d]);
        const float gate = bf2f(hg[rowbase + (size_t)i * 2048 + 1024 + d]);
        const float z  = sigf(gate);
        const float c  = sigf(-gate);
        const float gv = (hid >= 0.0f) ? (hid + 0.5f) : sigf(hid);
        h = fmaf(c, h, z * gv);
        Aacc *= c;
    }
    const size_t o = (size_t)(b * NCH + chunk) * Dh + d;
    Abuf[o]  = Aacc;
    hlbuf[o] = h;
}

__global__ __launch_bounds__(256) void scan_stage2(
    const float* __restrict__ Abuf, const float* __restrict__ hlbuf,
    float* __restrict__ Hs)
{
    const int g = blockIdx.x * 256 + threadIdx.x;   // 0..B*Dh-1
    const int d = g & (Dh - 1);
    const int b = g >> 10;
    float h = 0.0f;
    for (int ch = 0; ch < NCH; ++ch) {
        const size_t o = (size_t)(b * NCH + ch) * Dh + d;
        Hs[o] = h;
        h = fmaf(Abuf[o], h, hlbuf[o]);
    }
}

// replay chunk from Hs; write h (bf16) COMPACT into hout [M][1024]
__global__ __launch_bounds__(256) void scan_stage3(
    const ushort_t* __restrict__ hg, const float* __restrict__ Hs,
    ushort_t* __restrict__ hout)
{
    const int g     = blockIdx.x * 256 + threadIdx.x;
    const int d     = g & (Dh - 1);
    const int chunk = (g >> 10) & (NCH - 1);
    const int b     = g >> 16;
    const size_t rowbase = (size_t)(b * S + chunk * CL) * 2048;
    const size_t hbase   = (size_t)(b * S + chunk * CL) * 1024 + d;
    float h = Hs[(size_t)(b * NCH + chunk) * Dh + d];
    #pragma unroll 4
    for (int i = 0; i < CL; ++i) {
        const size_t ro = rowbase + (size_t)i * 2048;
        const float hid  = bf2f(hg[ro + d]);
        const float gate = bf2f(hg[ro + 1024 + d]);
        const float z  = sigf(gate);
        const float c  = sigf(-gate);
        const float gv = (hid >= 0.0f) ? (hid + 0.5f) : sigf(hid);
        h = fmaf(c, h, z * gv);
        hout[hbase + (size_t)i * 1024] = f2bf(h);
    }
}

extern "C" void kernel_launch(void* const* d_in, const int* in_sizes, int n_in,
                              void* d_out, int out_size, void* d_ws, size_t ws_size,
                              hipStream_t stream)
{
    (void)in_sizes; (void)n_in; (void)out_size; (void)ws_size;
    const float* x    = (const float*)d_in[0];
    const float* Whg  = (const float*)d_in[1];
    const float* Wout = (const float*)d_in[2];
    float* out = (float*)d_out;

    ushort_t* hgbuf = (ushort_t*)d_ws;                  // [M][2048] bf16  67.1 MB
    ushort_t* xb    = hgbuf + (size_t)M * 2048;         // [M][1024] bf16  33.5 MB (x, then h)
    ushort_t* whgb  = xb + (size_t)M * 1024;            // [2048][1024]     4.2 MB
    ushort_t* woutb = whgb + (size_t)2048 * 1024;       // [1024][1024]     2.1 MB
    float*    Abuf  = (float*)(woutb + (size_t)1024 * 1024);
    float*    hlbuf = Abuf + (size_t)Bsz * NCH * Dh;    // 1 MB each
    float*    Hsbuf = hlbuf + (size_t)Bsz * NCH * Dh;

    const dim3 blk(256);

    // fused conversion: (2097152 + 262144 + 131072)/256 = 9728 blocks
    cvt_all<<<dim3(9728), blk, 0, stream>>>(x, Whg, Wout, xb, whgb, woutb);

    // GEMM1: hg[M][2048] = x @ Whg^T  (bf16 out); grid 64x8 = 512
    gemm256<true><<<dim3(512), dim3(512), 0, stream>>>(
        xb, Din, whgb, Din, hgbuf, 2048, Din, 3);

    scan_stage1<<<dim3(Bsz * NCH * Dh / 256), blk, 0, stream>>>(hgbuf, Abuf, hlbuf);
    scan_stage2<<<dim3(Bsz * Dh / 256), blk, 0, stream>>>(Abuf, hlbuf, Hsbuf);
    scan_stage3<<<dim3(Bsz * NCH * Dh / 256), blk, 0, stream>>>(hgbuf, Hsbuf, xb);

    // GEMM2: out[M][1024] = h @ Wout^T  (f32 out); grid 64x4 = 256
    gemm256<false><<<dim3(256), dim3(512), 0, stream>>>(
        xb, Dh, woutb, Din, out, 1024, Dh, 2);
}